// Round 4
// baseline (186.603 us; speedup 1.0000x reference)
//
#include <hip/hip_runtime.h>
#include <hip/hip_cooperative_groups.h>
#include <math.h>

namespace cg = cooperative_groups;

#define A_N 5
#define NC 20
#define FD 38
#define SD (FD*FD)        // 1444
#define BD 32
#define OD 50
#define SA (SD*A_N)       // 7220
#define GX ((SA + 255) / 256)   // 29 blocks per batch
#define IGN_T 0.6f
#define OBJ_S 5.0f

__device__ __forceinline__ float sigm(float x) { return 1.0f / (1.0f + expf(-x)); }

// Single cooperative kernel. Phase 1 (all 928 blocks): stage GT boxes +
// responsibility keys in LDS; per (s,a) position compute max-IoU and the
// speculative loss split:
//   base = terms valid when n_pos[b]==1 (+ all responsible-position terms)
//   corr = conf^2 at ignored (m>=0.6) non-responsible positions (iff n_pos==0)
// Block partials -> ws (plain stores). grid.sync(). Phase 2 (block 0 only):
// OR flags per batch, combine 928 partials, write out.
__global__ __launch_bounds__(256) void k_all(
    const float* __restrict__ outputs, const float* __restrict__ targets,
    const float* __restrict__ anchors,
    float* __restrict__ pbase, float* __restrict__ pcorr, int* __restrict__ pflag,
    float* __restrict__ out)
{
    cg::grid_group grid = cg::this_grid();

    __shared__ float g_tlx[OD], g_tly[OD], g_brx[OD], g_bry[OD], g_den[OD];
    __shared__ int   s_cnt, s_any;
    __shared__ int   s_key[OD], s_cls[OD];
    __shared__ float s_gx[OD], s_gy[OD], s_gw[OD], s_gh[OD];
    __shared__ float wb[4], wc[4];

    const int b = blockIdx.y;
    const int tid = threadIdx.x;
    if (tid == 0) { s_cnt = 0; s_any = 0; }
    __syncthreads();

    if (tid < OD) {
        const float* t = targets + (b * OD + tid) * 5;
        float tx = t[0], ty = t[1], tw = t[2], th = t[3], tc = t[4];
        int key = -1;
        if (tx + ty + tw + th + tc > 0.0f) {
            float gx = tx * FD, gy = ty * FD, gw = tw * FD, gh = th * FD;
            float gtlx = gx - gw * 0.5f, gtly = gy - gh * 0.5f;
            float gbrx = gx + gw * 0.5f, gbry = gy + gh * 0.5f;
            // compacted box list for the max-IoU loop
            int k = atomicAdd(&s_cnt, 1);
            g_tlx[k] = gtlx; g_tly[k] = gtly;
            g_brx[k] = gbrx; g_bry[k] = gbry;
            g_den[k] = gw * gh + 1e-12f;
            // responsibility key: cell + argmax-anchor
            int cx = (int)floorf(gtlx), cy = (int)floorf(gtly);
            int cell = min(max(cy * FD + cx, 0), SD - 1);
            int ci = cell / FD, cj = cell - ci * FD;
            float acx = (float)cj + 0.5f, acy = (float)ci + 0.5f;
            float areaB = gw * gh;
            float best = -1.0f; int bi = 0;
            for (int a = 0; a < A_N; ++a) {
                float aw = anchors[2 * a] * FD, ah = anchors[2 * a + 1] * FD;
                float w = fmaxf(fminf(acx + aw * 0.5f, gbrx) - fmaxf(acx - aw * 0.5f, gtlx), 0.0f);
                float h = fmaxf(fminf(acy + ah * 0.5f, gbry) - fmaxf(acy - ah * 0.5f, gtly), 0.0f);
                float inter = w * h;
                float iou = inter / (aw * ah + areaB - inter + 1e-12f);
                if (iou > best) { best = iou; bi = a; }
            }
            key = bi * SD + cell;
            s_gx[tid] = gx; s_gy[tid] = gy; s_gw[tid] = gw; s_gh[tid] = gh;
            s_cls[tid] = (int)tc;
        }
        s_key[tid] = key;
    }
    __syncthreads();
    const int cnt = s_cnt;

    const int idx = blockIdx.x * 256 + tid;
    float base = 0.0f, corr = 0.0f;
    bool hot = false;
    if (idx < SA) {
        const int a = idx / SD;
        const int s = idx - a * SD;
        const int i = s / FD, j = s - i * FD;
        const float* ob = outputs + ((size_t)b * (A_N * (5 + NC)) + a * (5 + NC)) * SD + s;
        float o0 = ob[0 * SD], o1 = ob[1 * SD], o2 = ob[2 * SD], o3 = ob[3 * SD];
        float cr = ob[4 * SD];
        float aw = anchors[2 * a] * FD, ah = anchors[2 * a + 1] * FD;
        float px = sigm(o0) + (float)j;
        float py = sigm(o1) + (float)i;
        float pw = expf(o2) * aw;
        float ph = expf(o3) * ah;
        float ptlx = px - pw * 0.5f, ptly = py - ph * 0.5f;
        float pbrx = px + pw * 0.5f, pbry = py + ph * 0.5f;
        float areaA = pw * ph;

        float m = 0.0f;
        for (int o = 0; o < cnt; ++o) {
            float w = fmaxf(fminf(pbrx, g_brx[o]) - fmaxf(ptlx, g_tlx[o]), 0.0f);
            float h = fmaxf(fminf(pbry, g_bry[o]) - fmaxf(ptly, g_tly[o]), 0.0f);
            float inter = w * h;
            float iou = inter / (areaA + g_den[o] - inter);
            m = fmaxf(m, iou);
        }
        hot = (m > IGN_T);                       // strict >, for n_pos

        // responsibility: last match wins (ascending o == numpy fancy assign)
        int ro = -1;
        #pragma unroll 10
        for (int o = 0; o < OD; ++o) ro = (s_key[o] == idx) ? o : ro;

        float conf = sigm(cr);
        if (ro >= 0) {
            float d = conf - m;                  // iou loss, mask = OBJ_SCALE
            base += OBJ_S * OBJ_S * d * d;
            // box loss: pd = [sigm, sigm, exp, exp] (NO anchor scale on pd)
            float dx = s_gx[ro] - ((float)j + 0.5f);
            float dy = s_gy[ro] - ((float)i + 0.5f);
            float dw = s_gw[ro] / aw;
            float dh = s_gh[ro] / ah;
            float e0 = sigm(o0) - dx;
            float e1 = sigm(o1) - dy;
            float e2 = expf(o2) - dw;
            float e3 = expf(o3) - dh;
            base += e0*e0 + e1*e1 + e2*e2 + e3*e3;
            // class loss: ce = -log_softmax(softmax(x))[ct]
            int ct = s_cls[ro];
            float x[NC];
            float xmax = -INFINITY;
            #pragma unroll
            for (int k = 0; k < NC; ++k) { x[k] = ob[(5 + k) * SD]; xmax = fmaxf(xmax, x[k]); }
            float esum = 0.0f;
            #pragma unroll
            for (int k = 0; k < NC; ++k) { x[k] = expf(x[k] - xmax); esum += x[k]; }
            float inv = 1.0f / esum;
            float pmax = 0.0f, pct = 0.0f;
            #pragma unroll
            for (int k = 0; k < NC; ++k) {
                float p = x[k] * inv; x[k] = p;
                pmax = fmaxf(pmax, p);
                pct = (k == ct) ? p : pct;
            }
            float e2s = 0.0f;
            #pragma unroll
            for (int k = 0; k < NC; ++k) e2s += expf(x[k] - pmax);
            base += -(pct - (pmax + logf(e2s)));
        } else {
            float c2 = conf * conf;              // (conf*1 - 0)^2
            if (m < IGN_T) base += c2;           // kept even when n_pos==1
            else           corr += c2;           // only counts if n_pos==0
        }
    }

    unsigned long long bal = __ballot(hot);
    if ((tid & 63) == 0 && bal) atomicOr(&s_any, 1);

    // block reduction of (base, corr): wave64 shuffle + LDS across 4 waves
    #pragma unroll
    for (int off = 32; off > 0; off >>= 1) {
        base += __shfl_down(base, off);
        corr += __shfl_down(corr, off);
    }
    int lane = tid & 63, w = tid >> 6;
    if (lane == 0) { wb[w] = base; wc[w] = corr; }
    __syncthreads();
    if (tid == 0) {
        int gid = b * GX + blockIdx.x;
        pbase[gid] = wb[0] + wb[1] + wb[2] + wb[3];
        pcorr[gid] = wc[0] + wc[1] + wc[2] + wc[3];
        pflag[gid] = s_any;
        __threadfence();                         // device-scope: cross-XCD visibility
    }

    grid.sync();

    // ---- Phase 2: one block combines the 928 partials ----
    if (blockIdx.x == 0 && blockIdx.y == 0) {
        __shared__ int npos[BD];
        __shared__ float fsum[4];
        if (tid < BD) {
            int f = 0;
            for (int x = 0; x < GX; ++x) f |= pflag[tid * GX + x];
            npos[tid] = f;
        }
        __syncthreads();
        float sum = 0.0f;
        for (int g = tid; g < BD * GX; g += 256) {
            int bb = g / GX;
            sum += pbase[g] + (npos[bb] ? 0.0f : pcorr[g]);
        }
        #pragma unroll
        for (int off = 32; off > 0; off >>= 1) sum += __shfl_down(sum, off);
        if (lane == 0) fsum[w] = sum;
        __syncthreads();
        if (tid == 0) out[0] = (fsum[0] + fsum[1] + fsum[2] + fsum[3]) * (1.0f / (float)BD);
    }
}

extern "C" void kernel_launch(void* const* d_in, const int* in_sizes, int n_in,
                              void* d_out, int out_size, void* d_ws, size_t ws_size,
                              hipStream_t stream) {
    (void)in_sizes; (void)n_in; (void)out_size; (void)ws_size;
    const float* outputs = (const float*)d_in[0];
    const float* targets = (const float*)d_in[1];
    const float* anchors = (const float*)d_in[2];
    float* out = (float*)d_out;

    const int G = BD * GX;                        // 928 partial slots
    float* pbase = (float*)d_ws;
    float* pcorr = pbase + G;
    int*   pflag = (int*)(pcorr + G);

    void* args[] = { (void*)&outputs, (void*)&targets, (void*)&anchors,
                     (void*)&pbase, (void*)&pcorr, (void*)&pflag, (void*)&out };
    hipLaunchCooperativeKernel((void*)k_all, dim3(GX, BD), dim3(256),
                               args, 0, stream);
}

// Round 5
// 108.011 us; speedup vs baseline: 1.7276x; 1.7276x over previous
//
#include <hip/hip_runtime.h>
#include <math.h>

#define A_N 5
#define NC 20
#define FD 38
#define SD (FD*FD)        // 1444
#define BD 32
#define OD 50
#define SA (SD*A_N)       // 7220
#define GX ((SA + 255) / 256)   // 29 blocks per batch
#define NBLK (BD * GX)          // 928
#define IGN_T 0.6f
#define OBJ_S 5.0f
// d_ws is poisoned to 0xAA bytes before every launch -> counter starts here.
#define POISON_U32 0xAAAAAAAAu

__device__ __forceinline__ float sigm(float x) { return 1.0f / (1.0f + expf(-x)); }

// Single kernel, two phases, NO grid.sync (R4 showed it costs ~100us).
// Phase 1 (all 928 blocks): stage GT boxes + responsibility keys in LDS;
// per (s,a) position compute max-IoU and the speculative loss split:
//   base = terms valid when n_pos[b]==1 (+ all responsible-position terms)
//   corr = conf^2 at ignored (m>=0.6) non-responsible positions (iff n_pos==0)
// Each block stores partials, __threadfence(), bumps arrival counter.
// The LAST block to arrive (old == start+927) runs phase 2: OR flags per
// batch, combine 928 partials, write out. threadFenceReduction pattern —
// no co-residency assumption, no spin.
__global__ __launch_bounds__(256) void k_main(
    const float* __restrict__ outputs, const float* __restrict__ targets,
    const float* __restrict__ anchors,
    float* __restrict__ pbase, float* __restrict__ pcorr, int* __restrict__ pflag,
    unsigned int* __restrict__ counter, float* __restrict__ out)
{
    __shared__ float g_tlx[OD], g_tly[OD], g_brx[OD], g_bry[OD], g_den[OD];
    __shared__ int   s_cnt, s_any, s_last;
    __shared__ int   s_key[OD], s_cls[OD];
    __shared__ float s_gx[OD], s_gy[OD], s_gw[OD], s_gh[OD];
    __shared__ float wb[4], wc[4];

    const int b = blockIdx.y;
    const int tid = threadIdx.x;
    if (tid == 0) { s_cnt = 0; s_any = 0; }
    __syncthreads();

    if (tid < OD) {
        const float* t = targets + (b * OD + tid) * 5;
        float tx = t[0], ty = t[1], tw = t[2], th = t[3], tc = t[4];
        int key = -1;
        if (tx + ty + tw + th + tc > 0.0f) {
            float gx = tx * FD, gy = ty * FD, gw = tw * FD, gh = th * FD;
            float gtlx = gx - gw * 0.5f, gtly = gy - gh * 0.5f;
            float gbrx = gx + gw * 0.5f, gbry = gy + gh * 0.5f;
            // compacted box list for the max-IoU loop
            int k = atomicAdd(&s_cnt, 1);
            g_tlx[k] = gtlx; g_tly[k] = gtly;
            g_brx[k] = gbrx; g_bry[k] = gbry;
            g_den[k] = gw * gh + 1e-12f;
            // responsibility key: cell + argmax-anchor
            int cx = (int)floorf(gtlx), cy = (int)floorf(gtly);
            int cell = min(max(cy * FD + cx, 0), SD - 1);
            int ci = cell / FD, cj = cell - ci * FD;
            float acx = (float)cj + 0.5f, acy = (float)ci + 0.5f;
            float areaB = gw * gh;
            float best = -1.0f; int bi = 0;
            for (int a = 0; a < A_N; ++a) {
                float aw = anchors[2 * a] * FD, ah = anchors[2 * a + 1] * FD;
                float w = fmaxf(fminf(acx + aw * 0.5f, gbrx) - fmaxf(acx - aw * 0.5f, gtlx), 0.0f);
                float h = fmaxf(fminf(acy + ah * 0.5f, gbry) - fmaxf(acy - ah * 0.5f, gtly), 0.0f);
                float inter = w * h;
                float iou = inter / (aw * ah + areaB - inter + 1e-12f);
                if (iou > best) { best = iou; bi = a; }
            }
            key = bi * SD + cell;
            s_gx[tid] = gx; s_gy[tid] = gy; s_gw[tid] = gw; s_gh[tid] = gh;
            s_cls[tid] = (int)tc;
        }
        s_key[tid] = key;
    }
    __syncthreads();
    const int cnt = s_cnt;

    const int idx = blockIdx.x * 256 + tid;
    float base = 0.0f, corr = 0.0f;
    bool hot = false;
    if (idx < SA) {
        const int a = idx / SD;
        const int s = idx - a * SD;
        const int i = s / FD, j = s - i * FD;
        const float* ob = outputs + ((size_t)b * (A_N * (5 + NC)) + a * (5 + NC)) * SD + s;
        float o0 = ob[0 * SD], o1 = ob[1 * SD], o2 = ob[2 * SD], o3 = ob[3 * SD];
        float cr = ob[4 * SD];
        float aw = anchors[2 * a] * FD, ah = anchors[2 * a + 1] * FD;
        float px = sigm(o0) + (float)j;
        float py = sigm(o1) + (float)i;
        float pw = expf(o2) * aw;
        float ph = expf(o3) * ah;
        float ptlx = px - pw * 0.5f, ptly = py - ph * 0.5f;
        float pbrx = px + pw * 0.5f, pbry = py + ph * 0.5f;
        float areaA = pw * ph;

        float m = 0.0f;
        for (int o = 0; o < cnt; ++o) {
            float w = fmaxf(fminf(pbrx, g_brx[o]) - fmaxf(ptlx, g_tlx[o]), 0.0f);
            float h = fmaxf(fminf(pbry, g_bry[o]) - fmaxf(ptly, g_tly[o]), 0.0f);
            float inter = w * h;
            float iou = inter / (areaA + g_den[o] - inter);
            m = fmaxf(m, iou);
        }
        hot = (m > IGN_T);                       // strict >, for n_pos

        // responsibility: last match wins (ascending o == numpy fancy assign)
        int ro = -1;
        #pragma unroll 10
        for (int o = 0; o < OD; ++o) ro = (s_key[o] == idx) ? o : ro;

        float conf = sigm(cr);
        if (ro >= 0) {
            float d = conf - m;                  // iou loss, mask = OBJ_SCALE
            base += OBJ_S * OBJ_S * d * d;
            // box loss: pd = [sigm, sigm, exp, exp] (NO anchor scale on pd)
            float dx = s_gx[ro] - ((float)j + 0.5f);
            float dy = s_gy[ro] - ((float)i + 0.5f);
            float dw = s_gw[ro] / aw;
            float dh = s_gh[ro] / ah;
            float e0 = sigm(o0) - dx;
            float e1 = sigm(o1) - dy;
            float e2 = expf(o2) - dw;
            float e3 = expf(o3) - dh;
            base += e0*e0 + e1*e1 + e2*e2 + e3*e3;
            // class loss: ce = -log_softmax(softmax(x))[ct]
            int ct = s_cls[ro];
            float x[NC];
            float xmax = -INFINITY;
            #pragma unroll
            for (int k = 0; k < NC; ++k) { x[k] = ob[(5 + k) * SD]; xmax = fmaxf(xmax, x[k]); }
            float esum = 0.0f;
            #pragma unroll
            for (int k = 0; k < NC; ++k) { x[k] = expf(x[k] - xmax); esum += x[k]; }
            float inv = 1.0f / esum;
            float pmax = 0.0f, pct = 0.0f;
            #pragma unroll
            for (int k = 0; k < NC; ++k) {
                float p = x[k] * inv; x[k] = p;
                pmax = fmaxf(pmax, p);
                pct = (k == ct) ? p : pct;
            }
            float e2s = 0.0f;
            #pragma unroll
            for (int k = 0; k < NC; ++k) e2s += expf(x[k] - pmax);
            base += -(pct - (pmax + logf(e2s)));
        } else {
            float c2 = conf * conf;              // (conf*1 - 0)^2
            if (m < IGN_T) base += c2;           // kept even when n_pos==1
            else           corr += c2;           // only counts if n_pos==0
        }
    }

    unsigned long long bal = __ballot(hot);
    if ((tid & 63) == 0 && bal) atomicOr(&s_any, 1);

    // block reduction of (base, corr): wave64 shuffle + LDS across 4 waves
    #pragma unroll
    for (int off = 32; off > 0; off >>= 1) {
        base += __shfl_down(base, off);
        corr += __shfl_down(corr, off);
    }
    int lane = tid & 63, w = tid >> 6;
    if (lane == 0) { wb[w] = base; wc[w] = corr; }
    __syncthreads();
    if (tid == 0) {
        int gid = b * GX + blockIdx.x;
        pbase[gid] = wb[0] + wb[1] + wb[2] + wb[3];
        pcorr[gid] = wc[0] + wc[1] + wc[2] + wc[3];
        pflag[gid] = s_any;
        __threadfence();                         // release: partials visible device-wide
        unsigned int old = atomicAdd(counter, 1u);
        // ws is poisoned to 0xAA before every launch; accept zero-init too.
        s_last = (old == POISON_U32 + (NBLK - 1u)) || (old == (unsigned)(NBLK - 1));
        __threadfence();                         // acquire side for the last block
    }
    __syncthreads();

    // ---- Phase 2: only the LAST-arriving block runs this ----
    if (s_last) {
        __shared__ int npos[BD];
        __shared__ float fsum[4];
        if (tid < BD) {
            int f = 0;
            for (int x = 0; x < GX; ++x) f |= pflag[tid * GX + x];
            npos[tid] = f;
        }
        __syncthreads();
        float sum = 0.0f;
        for (int g = tid; g < NBLK; g += 256) {
            int bb = g / GX;
            sum += pbase[g] + (npos[bb] ? 0.0f : pcorr[g]);
        }
        #pragma unroll
        for (int off = 32; off > 0; off >>= 1) sum += __shfl_down(sum, off);
        if (lane == 0) fsum[w] = sum;
        __syncthreads();
        if (tid == 0) out[0] = (fsum[0] + fsum[1] + fsum[2] + fsum[3]) * (1.0f / (float)BD);
    }
}

extern "C" void kernel_launch(void* const* d_in, const int* in_sizes, int n_in,
                              void* d_out, int out_size, void* d_ws, size_t ws_size,
                              hipStream_t stream) {
    (void)in_sizes; (void)n_in; (void)out_size; (void)ws_size;
    const float* outputs = (const float*)d_in[0];
    const float* targets = (const float*)d_in[1];
    const float* anchors = (const float*)d_in[2];
    float* out = (float*)d_out;

    float* pbase = (float*)d_ws;
    float* pcorr = pbase + NBLK;
    int*   pflag = (int*)(pcorr + NBLK);
    unsigned int* counter = (unsigned int*)(pflag + NBLK);

    k_main<<<dim3(GX, BD), 256, 0, stream>>>(outputs, targets, anchors,
                                             pbase, pcorr, pflag, counter, out);
}

// Round 6
// 82.504 us; speedup vs baseline: 2.2617x; 1.3092x over previous
//
#include <hip/hip_runtime.h>
#include <math.h>

#define A_N 5
#define NC 20
#define FD 38
#define SD (FD*FD)        // 1444
#define BD 32
#define OD 50
#define SA (SD*A_N)       // 7220
#define HALF (SA/2)       // 3610 — each thread does p and p+HALF
#define GX ((HALF + 255) / 256)   // 15 blocks per batch
#define NBLK (BD * GX)            // 480
#define IGN_T 0.6f
#define OBJ_S 5.0f

__device__ __forceinline__ float sigm(float x) { return 1.0f / (1.0f + __expf(-x)); }

// Loss contribution for one (s,a) position given max-iou m and responsible
// object ro (-1 if none). base/corr: speculative split on n_pos (see k_main).
__device__ __forceinline__ void accum_loss(
    const float* __restrict__ ob, float m, int ro,
    float sx, float sy, float ew, float eh, float conf,
    float jj, float ii, float aw, float ah,
    const float* s_gx, const float* s_gy, const float* s_gw, const float* s_gh,
    const int* s_cls, float& base, float& corr)
{
    if (ro >= 0) {
        float d = conf - m;                  // iou loss, mask = OBJ_SCALE
        base += OBJ_S * OBJ_S * d * d;
        // box loss: pd = [sigm, sigm, exp, exp] (NO anchor scale on pd)
        float dx = s_gx[ro] - (jj + 0.5f);
        float dy = s_gy[ro] - (ii + 0.5f);
        float dw = s_gw[ro] / aw;
        float dh = s_gh[ro] / ah;
        float e0 = sx - dx, e1 = sy - dy, e2 = ew - dw, e3 = eh - dh;
        base += e0*e0 + e1*e1 + e2*e2 + e3*e3;
        // class loss: ce = -log_softmax(softmax(x))[ct]
        int ct = s_cls[ro];
        float x[NC];
        float xmax = -INFINITY;
        #pragma unroll
        for (int k = 0; k < NC; ++k) { x[k] = ob[(5 + k) * SD]; xmax = fmaxf(xmax, x[k]); }
        float esum = 0.0f;
        #pragma unroll
        for (int k = 0; k < NC; ++k) { x[k] = __expf(x[k] - xmax); esum += x[k]; }
        float inv = 1.0f / esum;
        float pmax = 0.0f, pct = 0.0f;
        #pragma unroll
        for (int k = 0; k < NC; ++k) {
            float p = x[k] * inv; x[k] = p;
            pmax = fmaxf(pmax, p);
            pct = (k == ct) ? p : pct;
        }
        float e2s = 0.0f;
        #pragma unroll
        for (int k = 0; k < NC; ++k) e2s += __expf(x[k] - pmax);
        base += -(pct - (pmax + __logf(e2s)));
    } else {
        float c2 = conf * conf;              // (conf*1 - 0)^2
        if (m < IGN_T) base += c2;           // kept even when n_pos==1
        else           corr += c2;           // only counts if n_pos==0
    }
}

// Phase-1 kernel: grid (GX, BD). Each thread handles positions p and p+HALF
// (2 independent strands -> ILP; shared LDS object reads). Division-free
// running max of IoU fractions via cross-multiplication; one divide at end.
__global__ __launch_bounds__(256) void k_main(
    const float* __restrict__ outputs, const float* __restrict__ targets,
    const float* __restrict__ anchors,
    float* __restrict__ pbase, float* __restrict__ pcorr, int* __restrict__ pflag)
{
    __shared__ float4 g_box[OD];              // (tlx, tly, brx, bry)
    __shared__ float  g_den[OD];              // area + 1e-12
    __shared__ float  s_traw[OD * 5];         // raw targets, coalesced staging
    __shared__ float  s_anc[2 * A_N];
    __shared__ int    s_cnt, s_any;
    __shared__ int    s_key[OD], s_cls[OD];
    __shared__ float  s_gx[OD], s_gy[OD], s_gw[OD], s_gh[OD];
    __shared__ float  wb[4], wc[4];

    const int b = blockIdx.y;
    const int tid = threadIdx.x;
    if (tid == 0) { s_cnt = 0; s_any = 0; }
    if (tid < OD * 5)  s_traw[tid] = targets[b * (OD * 5) + tid];
    if (tid < 2 * A_N) s_anc[tid]  = anchors[tid];

    // Issue this thread's global loads NOW so latency hides behind staging.
    const int ix = blockIdx.x * 256 + tid;
    const bool act = (ix < HALF);
    const int p0 = ix, p1 = ix + HALF;
    int a0 = p0 / SD, r0 = p0 - a0 * SD;
    int a1 = p1 / SD, r1 = p1 - a1 * SD;
    int ii0 = r0 / FD, jj0 = r0 - ii0 * FD;
    int ii1 = r1 / FD, jj1 = r1 - ii1 * FD;
    const float* ob0 = outputs + ((size_t)b * (A_N * (5 + NC)) + a0 * (5 + NC)) * SD + r0;
    const float* ob1 = outputs + ((size_t)b * (A_N * (5 + NC)) + a1 * (5 + NC)) * SD + r1;
    float q00 = 0, q01 = 0, q02 = 0, q03 = 0, q04 = 0;
    float q10 = 0, q11 = 0, q12 = 0, q13 = 0, q14 = 0;
    if (act) {
        q00 = ob0[0]; q01 = ob0[SD]; q02 = ob0[2 * SD]; q03 = ob0[3 * SD]; q04 = ob0[4 * SD];
        q10 = ob1[0]; q11 = ob1[SD]; q12 = ob1[2 * SD]; q13 = ob1[3 * SD]; q14 = ob1[4 * SD];
    }
    __syncthreads();

    if (tid < OD) {
        float tx = s_traw[tid * 5 + 0], ty = s_traw[tid * 5 + 1];
        float tw = s_traw[tid * 5 + 2], th = s_traw[tid * 5 + 3];
        float tc = s_traw[tid * 5 + 4];
        int key = -1;
        if (tx + ty + tw + th + tc > 0.0f) {
            float gx = tx * FD, gy = ty * FD, gw = tw * FD, gh = th * FD;
            float gtlx = gx - gw * 0.5f, gtly = gy - gh * 0.5f;
            float gbrx = gx + gw * 0.5f, gbry = gy + gh * 0.5f;
            int k = atomicAdd(&s_cnt, 1);
            g_box[k] = make_float4(gtlx, gtly, gbrx, gbry);
            g_den[k] = gw * gh + 1e-12f;
            // responsibility key: cell + argmax-anchor (first max wins, like np)
            int cx = (int)floorf(gtlx), cy = (int)floorf(gtly);
            int cell = min(max(cy * FD + cx, 0), SD - 1);
            int ci = cell / FD, cj = cell - ci * FD;
            float acx = (float)cj + 0.5f, acy = (float)ci + 0.5f;
            float areaB = gw * gh;
            float best = -1.0f; int bi = 0;
            for (int a = 0; a < A_N; ++a) {
                float aw = s_anc[2 * a] * FD, ah = s_anc[2 * a + 1] * FD;
                float w = fmaxf(fminf(acx + aw * 0.5f, gbrx) - fmaxf(acx - aw * 0.5f, gtlx), 0.0f);
                float h = fmaxf(fminf(acy + ah * 0.5f, gbry) - fmaxf(acy - ah * 0.5f, gtly), 0.0f);
                float inter = w * h;
                float iou = inter / (aw * ah + areaB - inter + 1e-12f);
                if (iou > best) { best = iou; bi = a; }
            }
            key = bi * SD + cell;
            s_gx[tid] = gx; s_gy[tid] = gy; s_gw[tid] = gw; s_gh[tid] = gh;
            s_cls[tid] = (int)tc;
        }
        s_key[tid] = key;
    }
    __syncthreads();
    const int cnt = s_cnt;

    float base = 0.0f, corr = 0.0f;
    bool hot = false;
    if (act) {
        float aw0 = s_anc[2 * a0] * FD, ah0 = s_anc[2 * a0 + 1] * FD;
        float aw1 = s_anc[2 * a1] * FD, ah1 = s_anc[2 * a1 + 1] * FD;
        float sx0 = sigm(q00), sy0 = sigm(q01), ew0 = __expf(q02), eh0 = __expf(q03);
        float sx1 = sigm(q10), sy1 = sigm(q11), ew1 = __expf(q12), eh1 = __expf(q13);
        float pw0 = ew0 * aw0, ph0 = eh0 * ah0;
        float pw1 = ew1 * aw1, ph1 = eh1 * ah1;
        float px0 = sx0 + (float)jj0, py0 = sy0 + (float)ii0;
        float px1 = sx1 + (float)jj1, py1 = sy1 + (float)ii1;
        float tlx0 = px0 - pw0 * 0.5f, tly0 = py0 - ph0 * 0.5f;
        float brx0 = px0 + pw0 * 0.5f, bry0 = py0 + ph0 * 0.5f;
        float tlx1 = px1 - pw1 * 0.5f, tly1 = py1 - ph1 * 0.5f;
        float brx1 = px1 + pw1 * 0.5f, bry1 = py1 + ph1 * 0.5f;
        float ar0 = pw0 * ph0, ar1 = pw1 * ph1;

        // division-free running max of inter/(ar + den - inter)
        float bn0 = 0.0f, bd0 = 1.0f, bn1 = 0.0f, bd1 = 1.0f;
        for (int o = 0; o < cnt; ++o) {
            float4 bx = g_box[o];
            float  dn = g_den[o];
            float w0 = fmaxf(fminf(brx0, bx.z) - fmaxf(tlx0, bx.x), 0.0f);
            float h0 = fmaxf(fminf(bry0, bx.w) - fmaxf(tly0, bx.y), 0.0f);
            float in0 = w0 * h0, de0 = ar0 + dn - in0;
            if (in0 * bd0 > bn0 * de0) { bn0 = in0; bd0 = de0; }
            float w1 = fmaxf(fminf(brx1, bx.z) - fmaxf(tlx1, bx.x), 0.0f);
            float h1 = fmaxf(fminf(bry1, bx.w) - fmaxf(tly1, bx.y), 0.0f);
            float in1 = w1 * h1, de1 = ar1 + dn - in1;
            if (in1 * bd1 > bn1 * de1) { bn1 = in1; bd1 = de1; }
        }
        float m0 = bn0 / bd0, m1 = bn1 / bd1;
        hot = (m0 > IGN_T) || (m1 > IGN_T);

        // responsibility: last match wins (ascending o == numpy fancy assign)
        int ro0 = -1, ro1 = -1;
        #pragma unroll 10
        for (int o = 0; o < OD; ++o) {
            int k = s_key[o];
            ro0 = (k == p0) ? o : ro0;
            ro1 = (k == p1) ? o : ro1;
        }
        float conf0 = sigm(q04), conf1 = sigm(q14);
        accum_loss(ob0, m0, ro0, sx0, sy0, ew0, eh0, conf0,
                   (float)jj0, (float)ii0, aw0, ah0,
                   s_gx, s_gy, s_gw, s_gh, s_cls, base, corr);
        accum_loss(ob1, m1, ro1, sx1, sy1, ew1, eh1, conf1,
                   (float)jj1, (float)ii1, aw1, ah1,
                   s_gx, s_gy, s_gw, s_gh, s_cls, base, corr);
    }

    unsigned long long bal = __ballot(hot);
    if ((tid & 63) == 0 && bal) atomicOr(&s_any, 1);

    #pragma unroll
    for (int off = 32; off > 0; off >>= 1) {
        base += __shfl_down(base, off);
        corr += __shfl_down(corr, off);
    }
    int lane = tid & 63, w = tid >> 6;
    if (lane == 0) { wb[w] = base; wc[w] = corr; }
    __syncthreads();
    if (tid == 0) {
        int gid = b * GX + blockIdx.x;
        pbase[gid] = wb[0] + wb[1] + wb[2] + wb[3];
        pcorr[gid] = wc[0] + wc[1] + wc[2] + wc[3];
        pflag[gid] = s_any;
    }
}

// Phase-2: combine 480 partials (kernel boundary = the grid-wide sync).
__global__ __launch_bounds__(256) void k_finish(
    const float* __restrict__ pbase, const float* __restrict__ pcorr,
    const int* __restrict__ pflag, float* __restrict__ out)
{
    __shared__ int npos[BD];
    __shared__ float wsum[4];
    const int tid = threadIdx.x;
    if (tid < BD) {
        int f = 0;
        for (int x = 0; x < GX; ++x) f |= pflag[tid * GX + x];
        npos[tid] = f;
    }
    __syncthreads();
    float sum = 0.0f;
    for (int g = tid; g < NBLK; g += 256) {
        int bb = g / GX;
        sum += pbase[g] + (npos[bb] ? 0.0f : pcorr[g]);
    }
    #pragma unroll
    for (int off = 32; off > 0; off >>= 1) sum += __shfl_down(sum, off);
    int lane = tid & 63, w = tid >> 6;
    if (lane == 0) wsum[w] = sum;
    __syncthreads();
    if (tid == 0) out[0] = (wsum[0] + wsum[1] + wsum[2] + wsum[3]) * (1.0f / (float)BD);
}

extern "C" void kernel_launch(void* const* d_in, const int* in_sizes, int n_in,
                              void* d_out, int out_size, void* d_ws, size_t ws_size,
                              hipStream_t stream) {
    (void)in_sizes; (void)n_in; (void)out_size; (void)ws_size;
    const float* outputs = (const float*)d_in[0];
    const float* targets = (const float*)d_in[1];
    const float* anchors = (const float*)d_in[2];
    float* out = (float*)d_out;

    float* pbase = (float*)d_ws;
    float* pcorr = pbase + NBLK;
    int*   pflag = (int*)(pcorr + NBLK);

    k_main<<<dim3(GX, BD), 256, 0, stream>>>(outputs, targets, anchors,
                                             pbase, pcorr, pflag);
    k_finish<<<dim3(1), 256, 0, stream>>>(pbase, pcorr, pflag, out);
}